// Round 1
// 104.629 us; speedup vs baseline: 1.0301x; 1.0301x over previous
//
#include <hip/hip_runtime.h>

#define NQ 2048
#define NO 2048
#define NOC 32   // o-chunks of 64

// ws layout (float offsets): P_h [NOC][2048][64] (= sum_o e*h_obs, pre-Wv),
// P_s [NOC][2048]. 17.04 MB total; ws_size ~256 MiB. NOTE (R0 analysis):
// dur_us includes 2x 256MiB harness poison fills (~87.3us); our kernels are
// ~20.5us of the 107.8us. Optimizing the kernel portion only.
constexpr size_t OFF_PH = 0;
constexpr size_t OFF_PS = (size_t)NOC * NQ * 64;

typedef _Float16 h2t __attribute__((ext_vector_type(2)));

#if defined(__has_builtin)
#if __has_builtin(__builtin_amdgcn_fdot2)
#define FDOT2(a, b, c) __builtin_amdgcn_fdot2((a), (b), (c), false)
#endif
#endif
#ifndef FDOT2
#define FDOT2(a, b, c) ((c) + (float)(a)[0] * (float)(b)[0] + (float)(a)[1] * (float)(b)[1])
#endif

__device__ __forceinline__ float pack2(float a, float b) {
    return __builtin_bit_cast(float, __builtin_amdgcn_cvt_pkrtz(a, b));
}
__device__ __forceinline__ h2t ash2(float f) {
    return __builtin_bit_cast(h2t, f);
}
__device__ __forceinline__ h2t relu2(h2t x) {
    return __builtin_elementwise_max(x, (h2t)(_Float16)0);
}

// ---------------------------------------------------------------------------
// Main: 1024 blocks = 32 q-groups x 32 o-chunks(64); 4 blocks/CU.
// lane=q. Phase A (f16-packed): hidden pair = pk_add + pk_max (relu), logits
// accumulate in f32 via v_dot2_f32_f16 against packed W2 — 3 VALU ops per
// TWO latents (halves the old fp32 op count). u/t tiles stored as float4 of
// 4 half2 (8 latents) per chunk c: tl2[c][o], ue[c][q]; all b128 accesses
// keep the contiguous conflict-free pattern. Phase B unchanged (f32, raw
// h_obs rows; Wv applied post-normalize in comb — linearity).
// ---------------------------------------------------------------------------
__global__ __launch_bounds__(256, 4) void gano_main(
    const float* __restrict__ h_obs,
    const float* __restrict__ pos_obs,
    const float* __restrict__ pos_query,
    const float* __restrict__ W1,
    const float* __restrict__ b1,
    const float* __restrict__ W2,
    float* __restrict__ Ph,
    float* __restrict__ Ps)
{
    __shared__ __align__(16) float tl2[8 * 64 * 4]; // [c][o] float4 = 4 half2 (l=8c..8c+7), 8KB
    __shared__ __align__(16) float ue[64 * 64];     // phase A: [c][q] float4 (first 8KB); after sync2: e [o][q] f32, 16KB
    __shared__ float w1q[3 * 64];                   // W1[0:3] + W1[6:9]
    __shared__ float w1o[3 * 64];                   // W1[3:6] - W1[6:9]
    __shared__ float b1l[64];
    __shared__ __align__(16) float w2h[32];         // packed half2 pairs of W2
    __shared__ float po[3 * 64];
    __shared__ float sbuf[4 * 64];

    const int tid  = threadIdx.x;
    const int lane = tid & 63;
    const int wave = __builtin_amdgcn_readfirstlane(tid >> 6);
    const int qg = blockIdx.x >> 5;   // 0..31
    const int oc = blockIdx.x & 31;   // 0..31
    const int obase = oc * 64;
    const int q = qg * 64 + lane;

    if (tid < 64) {
        float w6 = W1[6 * 64 + tid], w7 = W1[7 * 64 + tid], w8 = W1[8 * 64 + tid];
        w1q[0 * 64 + tid] = W1[0 * 64 + tid] + w6;
        w1q[1 * 64 + tid] = W1[1 * 64 + tid] + w7;
        w1q[2 * 64 + tid] = W1[2 * 64 + tid] + w8;
        w1o[0 * 64 + tid] = W1[3 * 64 + tid] - w6;
        w1o[1 * 64 + tid] = W1[4 * 64 + tid] - w7;
        w1o[2 * 64 + tid] = W1[5 * 64 + tid] - w8;
        b1l[tid] = b1[tid];
    }
    if (tid >= 64 && tid < 96) {
        int p = tid - 64;
        w2h[p] = pack2(W2[2 * p], W2[2 * p + 1]);   // W2 shape (64,1)
    }
    float pq0 = pos_query[q * 3 + 0];
    float pq1 = pos_query[q * 3 + 1];
    float pq2 = pos_query[q * 3 + 2];
    float po0 = pos_obs[(obase + lane) * 3 + 0];   // lane = o_local here
    float po1 = pos_obs[(obase + lane) * 3 + 1];
    float po2 = pos_obs[(obase + lane) * 3 + 2];
    if (wave == 0) { po[lane] = po0; po[64 + lane] = po1; po[128 + lane] = po2; }
    __syncthreads();   // sync0: weight staging visible

    // ---- t-tile: lane = o_local, wave w computes l in [16w,16w+16), packs f16 ----
    {
        float tv[16];
#pragma unroll
        for (int j = 0; j < 16; ++j) {
            int l = wave * 16 + j;
            tv[j] = po0 * w1o[l] + po1 * w1o[64 + l] + po2 * w1o[128 + l];
        }
        float4 p0, p1;
        p0.x = pack2(tv[0], tv[1]);  p0.y = pack2(tv[2], tv[3]);
        p0.z = pack2(tv[4], tv[5]);  p0.w = pack2(tv[6], tv[7]);
        p1.x = pack2(tv[8], tv[9]);  p1.y = pack2(tv[10], tv[11]);
        p1.z = pack2(tv[12], tv[13]); p1.w = pack2(tv[14], tv[15]);
        *(float4*)(tl2 + (size_t)((2 * wave) * 64 + lane) * 4) = p0;       // conflict-free b128
        *(float4*)(tl2 + (size_t)((2 * wave + 1) * 64 + lane) * 4) = p1;
    }
    // ---- u-tile: lane = q, chunk c = 2*wave+k covers l in [8c,8c+8), packed f16 ----
#pragma unroll
    for (int k = 0; k < 2; ++k) {
        const int c = wave * 2 + k;
        float uv[8];
#pragma unroll
        for (int d = 0; d < 8; ++d) {
            int l = c * 8 + d;
            uv[d] = b1l[l] + pq0 * w1q[l] + pq1 * w1q[64 + l] + pq2 * w1q[128 + l];
        }
        float4 up;
        up.x = pack2(uv[0], uv[1]); up.y = pack2(uv[2], uv[3]);
        up.z = pack2(uv[4], uv[5]); up.w = pack2(uv[6], uv[7]);
        *(float4*)(ue + (size_t)(c * 64 + lane) * 4) = up;                 // conflict-free b128
    }
    __syncthreads();   // sync1: tiles ready

    // ---- Phase A: wave w -> o-slice [16w,16w+16), lane = q, f16 packed ----
    float lg[16];
#pragma unroll
    for (int o = 0; o < 16; ++o) lg[o] = 0.f;
    const int ow = wave * 16;
#pragma unroll
    for (int c = 0; c < 8; ++c) {
        float4 u4 = *(const float4*)(ue + (size_t)(c * 64 + lane) * 4);    // per-lane b128, conflict-free
        float4 w4 = *(const float4*)(w2h + c * 4);                          // broadcast
        h2t u0 = ash2(u4.x), u1 = ash2(u4.y), u2 = ash2(u4.z), u3 = ash2(u4.w);
        h2t w0 = ash2(w4.x), w1 = ash2(w4.y), w2 = ash2(w4.z), w3 = ash2(w4.w);
        const float4* tr = (const float4*)tl2 + (c * 64 + ow);              // broadcast rows
#pragma unroll
        for (int j = 0; j < 16; ++j) {
            float4 t4 = tr[j];
            h2t a0 = relu2(u0 + ash2(t4.x));
            h2t a1 = relu2(u1 + ash2(t4.y));
            h2t a2 = relu2(u2 + ash2(t4.z));
            h2t a3 = relu2(u3 + ash2(t4.w));
            float acc = lg[j];
            acc = FDOT2(a0, w0, acc);
            acc = FDOT2(a1, w1, acc);
            acc = FDOT2(a2, w2, acc);
            acc = FDOT2(a3, w3, acc);
            lg[j] = acc;
        }
    }
    // ---- mask + exp (logits O(1): raw exp safe) ----
    float e[16], spart = 0.f;
#pragma unroll
    for (int o = 0; o < 16; ++o) {
        float d0 = pq0 - po[ow + o];
        float d1 = pq1 - po[64 + ow + o];
        float d2 = pq2 - po[128 + ow + o];
        float dd = d0 * d0 + d1 * d1 + d2 * d2;
        float ev = (dd > 0.25f) ? 0.f : __expf(lg[o]);
        e[o] = ev; spart += ev;
    }
    __syncthreads();   // sync2: phase A done reading ue -> reuse as e-buf
#pragma unroll
    for (int o = 0; o < 16; ++o) ue[(size_t)(ow + o) * 64 + lane] = e[o];  // conflict-free
    sbuf[wave * 64 + lane] = spart;
    __syncthreads();   // sync3: e-buf ready

    // ---- Phase B: wave w -> l-slice [16w,16w+16), full 64 o's, raw h_obs ----
    float h0 = 0.f, h1 = 0.f, h2 = 0.f, h3 = 0.f, h4 = 0.f, h5 = 0.f, h6 = 0.f, h7 = 0.f;
    float h8 = 0.f, h9 = 0.f, hA = 0.f, hB = 0.f, hC = 0.f, hD = 0.f, hE = 0.f, hF = 0.f;
    const float* vb = h_obs + (size_t)obase * 64 + ow;   // ow doubles as l-offset
#pragma unroll 4
    for (int o = 0; o < 64; ++o) {
        float eo = ue[(size_t)o * 64 + lane];        // b32, lane-consecutive
        const float4* vr = (const float4*)(vb + (size_t)o * 64);  // wave-uniform, L2-hot
        float4 v0 = vr[0], v1 = vr[1], v2 = vr[2], v3 = vr[3];
        h0 += eo * v0.x; h1 += eo * v0.y; h2 += eo * v0.z; h3 += eo * v0.w;
        h4 += eo * v1.x; h5 += eo * v1.y; h6 += eo * v1.z; h7 += eo * v1.w;
        h8 += eo * v2.x; h9 += eo * v2.y; hA += eo * v2.z; hB += eo * v2.w;
        hC += eo * v3.x; hD += eo * v3.y; hE += eo * v3.z; hF += eo * v3.w;
    }

    // ---- store partials (disjoint per wave, no combine) ----
    float* hp = Ph + ((size_t)oc * NQ + (size_t)qg * 64 + lane) * 64 + ow;
    ((float4*)hp)[0] = make_float4(h0, h1, h2, h3);
    ((float4*)hp)[1] = make_float4(h4, h5, h6, h7);
    ((float4*)hp)[2] = make_float4(h8, h9, hA, hB);
    ((float4*)hp)[3] = make_float4(hC, hD, hE, hF);
    if (wave == 0) {
        float s = sbuf[lane] + sbuf[64 + lane] + sbuf[128 + lane] + sbuf[192 + lane];
        Ps[(size_t)oc * NQ + (size_t)qg * 64 + lane] = s;
    }
}

// ---------------------------------------------------------------------------
// Combine + Wv projection: g[q][k] = sum_c Ph[c][q][k]; s = sum_c Ps[c][q];
// out[q][l] = (g[q][:]/s) @ Wv + bv.  512 blocks; block = 4 q; wave w owns
// query w; Wv staged in LDS (lane-consecutive b32 reads, conflict-free).
// ---------------------------------------------------------------------------
__global__ __launch_bounds__(256, 2) void gano_comb(
    const float* __restrict__ Ph,
    const float* __restrict__ Ps,
    const float* __restrict__ Wv,
    const float* __restrict__ bv,
    float* __restrict__ out)
{
    __shared__ __align__(16) float wv[64 * 64];
    __shared__ __align__(16) float g[4 * 68];   // [qi][k], k=64 holds s; stride 68 (272B, 16B-aligned)
    const int tid  = threadIdx.x;
    const int lane = tid & 63;
    const int wave = tid >> 6;
    const int q0 = blockIdx.x * 4;
    {
        const float4* src = (const float4*)Wv;
        float4* dst = (float4*)wv;
#pragma unroll
        for (int k = 0; k < 4; ++k) dst[tid + k * 256] = src[tid + k * 256];
    }
    // chunk-sum: thread (qi=wave, k=lane): coalesced across lanes
    {
        const int qi = wave, k = lane;
        float acc = 0.f;
#pragma unroll
        for (int c = 0; c < NOC; ++c)
            acc += Ph[((size_t)c * NQ + q0 + qi) * 64 + k];
        g[qi * 68 + k] = acc;
        if (k == 0) {
            float ss = 0.f;
#pragma unroll
            for (int c = 0; c < NOC; ++c) ss += Ps[(size_t)c * NQ + q0 + qi];
            g[qi * 68 + 64] = ss;
        }
    }
    __syncthreads();
    // matvec: wave w -> query q0+w; lane = output latent l
    const float* gq = g + wave * 68;            // wave-uniform broadcast
    float inv = 1.0f / gq[64];
    float a0 = 0.f, a1 = 0.f, a2 = 0.f, a3 = 0.f;
#pragma unroll
    for (int kb = 0; kb < 16; ++kb) {
        float4 g4 = *(const float4*)(gq + kb * 4);
        a0 += g4.x * wv[(kb * 4 + 0) * 64 + lane];
        a1 += g4.y * wv[(kb * 4 + 1) * 64 + lane];
        a2 += g4.z * wv[(kb * 4 + 2) * 64 + lane];
        a3 += g4.w * wv[(kb * 4 + 3) * 64 + lane];
    }
    out[(size_t)(q0 + wave) * 64 + lane] = ((a0 + a1) + (a2 + a3)) * inv + bv[lane];
}

// ---------------------------------------------------------------------------
extern "C" void kernel_launch(void* const* d_in, const int* in_sizes, int n_in,
                              void* d_out, int out_size, void* d_ws, size_t ws_size,
                              hipStream_t stream) {
    const float* h_obs     = (const float*)d_in[0];
    // d_in[1] = x_obs (unused by reference)
    const float* pos_obs   = (const float*)d_in[2];
    const float* pos_query = (const float*)d_in[3];
    const float* W1        = (const float*)d_in[4];
    const float* b1        = (const float*)d_in[5];
    const float* W2        = (const float*)d_in[6];
    // d_in[7] = b2: constant shift, cancels in softmax
    const float* Wv        = (const float*)d_in[8];
    const float* bv        = (const float*)d_in[9];
    float* ws  = (float*)d_ws;
    float* out = (float*)d_out;

    gano_main<<<dim3(1024), dim3(256), 0, stream>>>(h_obs, pos_obs, pos_query, W1, b1, W2,
                                                    ws + OFF_PH, ws + OFF_PS);
    gano_comb<<<dim3(NQ / 4), dim3(256), 0, stream>>>(ws + OFF_PH, ws + OFF_PS, Wv, bv, out);
}